// Round 8
// baseline (901.682 us; speedup 1.0000x reference)
//
#include <hip/hip_runtime.h>
#include <hip/hip_bf16.h>
#include <hip/hip_cooperative_groups.h>

#define N_CRYST 64
#define ATOMS_PER 32
#define NN 2048
#define NBRS 20
#define EE 40960
#define CC 128
#define HIDDIM 256
#define NBASIS 128
#define NLAYERS 8
#define LMAXV 6
#define KK 19
#define MAXZV 100
#define ZDIMV 256
#define FOUR_PI_F 12.566370614359172f

namespace cg = cooperative_groups;

typedef unsigned short ushort_t;
typedef __attribute__((ext_vector_type(8))) short short8;
typedef __attribute__((ext_vector_type(4))) float floatx4;

__device__ __forceinline__ ushort_t f2us(float f) {
    union { float f; unsigned u; } x;
    x.f = f;
    unsigned r = (x.u + 0x7fffu + ((x.u >> 16) & 1u)) >> 16;
    return (ushort_t)r;
}
__device__ __forceinline__ float us2f(unsigned u) {  // low 16 bits = bf16
    return __uint_as_float(u << 16);
}

// ---------------- lattice + positions ----------------
__global__ void k_pos(const float* __restrict__ frac, const float* __restrict__ lengths,
                      const float* __restrict__ angles, const int* __restrict__ batch,
                      float* __restrict__ pos) {
    int n = blockIdx.x * blockDim.x + threadIdx.x;
    if (n >= NN) return;
    int b = batch[n];
    float la = lengths[b * 3 + 0];
    float lb = lengths[b * 3 + 1];
    float lc = lengths[b * 3 + 2];
    const float D2R = 0.017453292519943295f;
    float aa = angles[b * 3 + 0] * D2R;
    float ab = angles[b * 3 + 1] * D2R;
    float ag = angles[b * 3 + 2] * D2R;
    float ca = cosf(aa), cb = cosf(ab), cg = cosf(ag), sg = sinf(ag);
    float v3y = (ca - cb * cg) / sg;
    float v3z = sqrtf(fmaxf(1.0f - cb * cb - v3y * v3y, 1e-8f));
    float f0 = frac[n * 3 + 0];
    float f1 = frac[n * 3 + 1];
    float f2 = frac[n * 3 + 2];
    pos[n * 3 + 0] = f0 * la + f1 * (lb * cg) + f2 * (lc * cb);
    pos[n * 3 + 1] = f1 * (lb * sg) + f2 * (lc * v3y);
    pos[n * 3 + 2] = f2 * (lc * v3z);
}

// ---------------- edge geometry; Y padded to 20 (Ypad[e][19]=0) ----------------
__global__ void k_edge(const int* __restrict__ ei, const float* __restrict__ pos,
                       float* __restrict__ dist, float* __restrict__ dirn,
                       float* __restrict__ Ypad) {
    int e = blockIdx.x * blockDim.x + threadIdx.x;
    if (e >= EE) return;
    int s = ei[e], d = ei[EE + e];
    float vx = pos[s * 3 + 0] - pos[d * 3 + 0];
    float vy = pos[s * 3 + 1] - pos[d * 3 + 1];
    float vz = pos[s * 3 + 2] - pos[d * 3 + 2];
    float dd = sqrtf(vx * vx + vy * vy + vz * vz) + 1e-8f;
    float ix = vx / dd, iy = vy / dd, iz = vz / dd;
    dist[e] = dd;
    dirn[e * 3 + 0] = ix;
    dirn[e * 3 + 1] = iy;
    dirn[e * 3 + 2] = iz;

    float ct = iz;
    float rho = sqrtf(ix * ix + iy * iy) + 1e-12f;
    float cph = ix / rho, sph = iy / rho;
    float P0[LMAXV + 1];
    float P1[LMAXV + 1];
    P0[0] = 1.0f;
    P0[1] = ct;
    #pragma unroll
    for (int l = 2; l <= LMAXV; l++)
        P0[l] = ((2 * l - 1) * ct * P0[l - 1] - (l - 1) * P0[l - 2]) / (float)l;
    P1[0] = 0.0f;
    P1[1] = -rho;
    P1[2] = -3.0f * ct * rho;
    #pragma unroll
    for (int l = 3; l <= LMAXV; l++)
        P1[l] = ((2 * l - 1) * ct * P1[l - 1] - l * P1[l - 2]) / (float)(l - 1);

    float* Ye = Ypad + (size_t)e * 20;
    Ye[0] = 0.28209479177387814f;
    #pragma unroll
    for (int l = 1; l <= LMAXV; l++) {
        float K0 = sqrtf((2 * l + 1) / FOUR_PI_F);
        float K1 = sqrtf(2.0f * (2 * l + 1) / (FOUR_PI_F * l * (l + 1)));
        Ye[3 * l - 2] = K1 * P1[l] * sph;
        Ye[3 * l - 1] = K0 * P0[l];
        Ye[3 * l]     = K1 * P1[l] * cph;
    }
    Ye[19] = 0.0f;
}

// ---------------- per-block CSR over the block's 160 edges, grouped by src atom ----------------
__global__ void k_bcsr(const int* __restrict__ ei, int* __restrict__ bptr,
                       unsigned char* __restrict__ bedge) {
    int b = blockIdx.x;  // 256 blocks x 64 threads
    int t = threadIdx.x;
    __shared__ int cnt[32], base[32];
    if (t < 32) cnt[t] = 0;
    __syncthreads();
    int e0 = b * 160, crb = (b >> 2) * 32;
    for (int j = t; j < 160; j += 64) {
        int a = ei[e0 + j] - crb;
        atomicAdd(&cnt[a], 1);
    }
    __syncthreads();
    if (t == 0) {
        int run = 0;
        for (int a = 0; a < 32; a++) {
            base[a] = run;
            bptr[b * 33 + a] = run;
            run += cnt[a];
        }
        bptr[b * 33 + 32] = run;
    }
    __syncthreads();
    if (t < 32) cnt[t] = 0;
    __syncthreads();
    for (int j = t; j < 160; j += 64) {
        int a = ei[e0 + j] - crb;
        int slot = base[a] + atomicAdd(&cnt[a], 1);
        bedge[b * 160 + slot] = (unsigned char)j;
    }
}

// ---------------- rbf -> bf16, compact [E][128] (layer-invariant) ----------------
__global__ void k_rbfA(const float* __restrict__ dist, ushort_t* __restrict__ Abf2) {
    int idx = blockIdx.x * blockDim.x + threadIdx.x;
    if (idx >= EE * NBASIS) return;
    int e = idx >> 7, j = idx & 127;
    const float width = 8.0f / 127.0f;
    const float invw = 127.0f / 8.0f;
    float t = (dist[e] - (float)j * width) * invw;
    Abf2[idx] = f2us(expf(-0.5f * t * t));
}

// ---------------- weight transpose+cast ----------------
__global__ void k_wt(const float* __restrict__ W1, const float* __restrict__ Wd,
                     const float* __restrict__ W2,
                     ushort_t* __restrict__ WT1, ushort_t* __restrict__ WT2) {
    int idx = blockIdx.x * blockDim.x + threadIdx.x;
    const int n1 = NLAYERS * HIDDIM * 256;
    if (idx < n1) {
        int l = idx >> 16;
        int r = idx & 65535;
        int n = r >> 8, k = r & 255;
        float v = (k < 128) ? W1[((size_t)l * CC + k) * HIDDIM + n]
                            : Wd[((size_t)l * NBASIS + (k - 128)) * HIDDIM + n];
        WT1[idx] = f2us(v);
    } else {
        int j = idx - n1;
        if (j >= NLAYERS * CC * HIDDIM) return;
        int l = j >> 15;
        int r = j & 32767;
        int n = r >> 8, k = r & 255;
        WT2[j] = f2us(W2[((size_t)l * HIDDIM + k) * CC + n]);
    }
}

// ---------------- z @ zproj ----------------
__global__ void k_zc(const float* __restrict__ z, const float* __restrict__ zproj,
                     float* __restrict__ zc) {
    int idx = blockIdx.x * blockDim.x + threadIdx.x;
    if (idx >= N_CRYST * CC) return;
    int b = idx >> 7, c = idx & 127;
    float acc = 0.0f;
    for (int d = 0; d < ZDIMV; d++)
        acc += z[b * ZDIMV + d] * zproj[d * CC + c];
    zc[idx] = acc;
}

// ---------------- init x (bf16 state) ----------------
__global__ void k_xinit(const int* __restrict__ atype, const int* __restrict__ batch,
                        const float* __restrict__ emb, const float* __restrict__ zc,
                        ushort_t* __restrict__ x) {
    int idx = blockIdx.x * blockDim.x + threadIdx.x;
    if (idx >= NN * KK * CC) return;
    int n = idx / (KK * CC);
    int r = idx - n * (KK * CC);
    float v = 0.0f;
    if (r < CC) v = emb[atype[n] * CC + r] + zc[batch[n] * CC + r];
    x[idx] = f2us(v);
}

// ---------------- persistent cooperative kernel: all 8 layers ----------------
// grid 256 x 512 (8 waves, 2M x 4N). Block owns 8 nodes / 160 edges.
// Per layer: [grid.sync] -> gemm1 8 k-chunks of 32 (chunks 0-3: s computed in-block
// via per-block CSR; 4-7: rbf staged from global) -> gemm2 8 chunks -> agg.
// LDS 53760 B: As[160][40] @0 (alias Hs); Bs[256][40] @12800 (alias B2s[128][40]);
//              Ms[160][128] @0; Ys[160][20] f32 @40960 (persistent).
__global__ __launch_bounds__(512, 1) void k_layers(
        const ushort_t* __restrict__ Abf2, const ushort_t* __restrict__ WT1,
        const ushort_t* __restrict__ WT2, const float* __restrict__ Ypad,
        ushort_t* x, const int* __restrict__ bptr,
        const unsigned char* __restrict__ bedge) {
    cg::grid_group gridg = cg::this_grid();
    __shared__ char smraw[53760];
    ushort_t* As  = (ushort_t*)smraw;             // [160][40]
    ushort_t* Bs  = (ushort_t*)(smraw + 12800);   // [256][40]
    ushort_t* Hs  = (ushort_t*)smraw;             // [160][40] alias
    ushort_t* B2s = (ushort_t*)(smraw + 12800);   // [128][40] alias
    ushort_t* Ms  = (ushort_t*)smraw;             // [160][128]
    float* Ys     = (float*)(smraw + 40960);      // [160][20]

    int b = blockIdx.x;
    int t = threadIdx.x;
    int e0 = b * 160;
    int crb = (b >> 2) * 32;
    int w = t >> 6, lane = t & 63;
    int quad = lane >> 4, lrow = lane & 15;
    int wm = (w & 1) * 80;
    int wn = (w >> 1) * 64;
    int wn2 = (w >> 1) * 32;

    // stage Y once (layer-invariant; region never clobbered)
    for (int i = t; i < 160 * 20; i += 512) Ys[i] = Ypad[(size_t)e0 * 20 + i];

    int sa = t >> 4;          // s-role atom 0..31
    int scp = t & 15;         // s-role col-pair 0..15
    int si0 = bptr[b * 33 + sa];
    int si1 = bptr[b * 33 + sa + 1];

    for (int l = 0; l < NLAYERS; l++) {
        gridg.sync();   // x from previous layer (all blocks) visible; also Ys barrier at l=0
        const ushort_t* W1l = WT1 + (size_t)l * 65536;
        const ushort_t* W2l = WT2 + (size_t)l * 32768;

        floatx4 acc1[5][4];
        #pragma unroll
        for (int mi = 0; mi < 5; mi++)
            #pragma unroll
            for (int ni = 0; ni < 4; ni++)
                acc1[mi][ni] = (floatx4){0.f, 0.f, 0.f, 0.f};

        // -------- GEMM1: 8 k-chunks of 32 --------
        for (int c = 0; c < 8; c++) {
            __syncthreads();
            if (c < 4) {
                // s chunk: compute s[e, c*32 + scp*2 (+1)] for my atom's edges
                int c2 = c * 32 + scp * 2;
                const ushort_t* xp = x + (size_t)(crb + sa) * (KK * CC) + c2;
                float2 xr[KK];
                #pragma unroll
                for (int k = 0; k < KK; k++) {
                    unsigned u = *(const unsigned*)(xp + k * CC);
                    xr[k].x = us2f(u & 0xffffu);
                    xr[k].y = us2f(u >> 16);
                }
                for (int i = si0; i < si1; i++) {
                    int eL = bedge[b * 160 + i];
                    const float* yp = &Ys[eL * 20];
                    float ax = 0.f, ay = 0.f;
                    #pragma unroll
                    for (int k = 0; k < KK; k++) {
                        float y = yp[k];
                        ax += y * xr[k].x;
                        ay += y * xr[k].y;
                    }
                    unsigned pk = (unsigned)f2us(ax) | (((unsigned)f2us(ay)) << 16);
                    *(unsigned*)&As[eL * 40 + scp * 2] = pk;
                }
            } else {
                // rbf chunk from global (160 x 32 = 640 vec8)
                #pragma unroll
                for (int i = 0; i < 2; i++) {
                    int idx = i * 512 + t;
                    if (idx < 640) {
                        int r = idx >> 2, kc = (idx & 3) * 8;
                        *(short8*)&As[r * 40 + kc] =
                            *(const short8*)&Abf2[(size_t)(e0 + r) * 128 + (c - 4) * 32 + kc];
                    }
                }
            }
            // stage B1 chunk (256 x 32 = 1024 vec8)
            #pragma unroll
            for (int i = 0; i < 2; i++) {
                int idx = i * 512 + t;
                int r = idx >> 2, kc = (idx & 3) * 8;
                *(short8*)&Bs[r * 40 + kc] =
                    *(const short8*)&W1l[(size_t)r * 256 + c * 32 + kc];
            }
            __syncthreads();
            int kk = quad * 8;
            short8 af[5], bf[4];
            #pragma unroll
            for (int mi = 0; mi < 5; mi++)
                af[mi] = *(const short8*)&As[(wm + mi * 16 + lrow) * 40 + kk];
            #pragma unroll
            for (int ni = 0; ni < 4; ni++)
                bf[ni] = *(const short8*)&Bs[(wn + ni * 16 + lrow) * 40 + kk];
            #pragma unroll
            for (int mi = 0; mi < 5; mi++)
                #pragma unroll
                for (int ni = 0; ni < 4; ni++)
                    acc1[mi][ni] = __builtin_amdgcn_mfma_f32_16x16x32_bf16(
                        af[mi], bf[ni], acc1[mi][ni], 0, 0, 0);
        }

        // -------- GEMM2: m[160,128] = silu(h) @ WT2^T, 8 k-chunks of 32 --------
        floatx4 macc[5][2];
        #pragma unroll
        for (int mi = 0; mi < 5; mi++)
            #pragma unroll
            for (int ni = 0; ni < 2; ni++)
                macc[mi][ni] = (floatx4){0.f, 0.f, 0.f, 0.f};

        #pragma unroll
        for (int nc = 0; nc < 8; nc++) {
            __syncthreads();
            if ((w >> 1) == (nc >> 1)) {  // the 2 waves owning h cols [nc*32, nc*32+32)
                int nib = (nc & 1) * 2;
                #pragma unroll
                for (int mi = 0; mi < 5; mi++) {
                    int row = wm + mi * 16 + quad * 4;
                    #pragma unroll
                    for (int nii = 0; nii < 2; nii++) {
                        int colL = nii * 16 + lrow;
                        #pragma unroll
                        for (int r = 0; r < 4; r++) {
                            float v = acc1[mi][nib + nii][r];
                            v = v / (1.0f + __expf(-v));
                            Hs[(row + r) * 40 + colL] = f2us(v);
                        }
                    }
                }
            }
            {   // stage B2 chunk (128 x 32 = 512 vec8, 1/thr)
                int r = t >> 2, kc = (t & 3) * 8;
                *(short8*)&B2s[r * 40 + kc] =
                    *(const short8*)&W2l[(size_t)r * 256 + nc * 32 + kc];
            }
            __syncthreads();
            int kk = quad * 8;
            short8 af[5], bf2[2];
            #pragma unroll
            for (int mi = 0; mi < 5; mi++)
                af[mi] = *(const short8*)&Hs[(wm + mi * 16 + lrow) * 40 + kk];
            #pragma unroll
            for (int ni = 0; ni < 2; ni++)
                bf2[ni] = *(const short8*)&B2s[(wn2 + ni * 16 + lrow) * 40 + kk];
            #pragma unroll
            for (int mi = 0; mi < 5; mi++)
                #pragma unroll
                for (int ni = 0; ni < 2; ni++)
                    macc[mi][ni] = __builtin_amdgcn_mfma_f32_16x16x32_bf16(
                        af[mi], bf2[ni], macc[mi][ni], 0, 0, 0);
        }

        __syncthreads();
        #pragma unroll
        for (int mi = 0; mi < 5; mi++) {  // macc -> Ms bf16 [160][128]
            int row = wm + mi * 16 + quad * 4;
            #pragma unroll
            for (int ni = 0; ni < 2; ni++) {
                int col = wn2 + ni * 16 + lrow;
                #pragma unroll
                for (int r = 0; r < 4; r++)
                    Ms[(row + r) * 128 + col] = f2us(macc[mi][ni][r]);
            }
        }
        __syncthreads();

        // -------- aggregation: wave = node (8), lane = col-pair --------
        int c2 = lane * 2;
        float2 xacc[KK];
        #pragma unroll
        for (int k = 0; k < KK; k++) xacc[k] = make_float2(0.f, 0.f);

        #pragma unroll
        for (int j = 0; j < NBRS; j++) {
            int eg = w * NBRS + j;
            unsigned mv = *(const unsigned*)&Ms[eg * 128 + c2];
            float mx = us2f(mv & 0xffffu);
            float my = us2f(mv >> 16);
            const float* yp = &Ys[eg * 20];
            #pragma unroll
            for (int kq = 0; kq < 5; kq++) {
                float4 y = *(const float4*)(yp + kq * 4);
                int k = kq * 4;
                xacc[k + 0].x += y.x * mx; xacc[k + 0].y += y.x * my;
                xacc[k + 1].x += y.y * mx; xacc[k + 1].y += y.y * my;
                xacc[k + 2].x += y.z * mx; xacc[k + 2].y += y.z * my;
                if (kq < 4) {
                    xacc[k + 3].x += y.w * mx; xacc[k + 3].y += y.w * my;
                }
            }
        }
        const float s = 1.0f / (float)NBRS;
        ushort_t* xp = x + (size_t)(b * 8 + w) * (KK * CC) + c2;
        #pragma unroll
        for (int k = 0; k < KK; k++) {
            unsigned u = *(const unsigned*)(xp + k * CC);
            float ox = us2f(u & 0xffffu) + xacc[k].x * s;
            float oy = us2f(u >> 16) + xacc[k].y * s;
            unsigned pk = (unsigned)f2us(ox) | (((unsigned)f2us(oy)) << 16);
            *(unsigned*)(xp + k * CC) = pk;
        }
    }
}

// ---------------- atom logits ----------------
__global__ void k_logits(const ushort_t* __restrict__ x, const float* __restrict__ Wa,
                         const float* __restrict__ ba, float* __restrict__ out) {
    int idx = blockIdx.x * blockDim.x + threadIdx.x;
    if (idx >= NN * MAXZV) return;
    int n = idx / MAXZV, a = idx - n * MAXZV;
    float acc = ba[a];
    const ushort_t* hn = x + (size_t)n * (KK * CC);
    for (int c = 0; c < CC; c++) acc += us2f(hn[c]) * Wa[c * MAXZV + a];
    out[idx] = acc;
}

// ---------------- coord_diff ----------------
__global__ void k_coord(const int* __restrict__ ei, const ushort_t* __restrict__ x,
                        const float* __restrict__ wf, const float* __restrict__ dirn,
                        float* __restrict__ out) {
    int n = blockIdx.x;
    int t = threadIdx.x;  // 64
    __shared__ float fs[NBRS];
    __shared__ float wsh[CC];
    wsh[t] = wf[t];
    wsh[t + 64] = wf[t + 64];
    __syncthreads();
    if (t < NBRS) {
        int e = n * NBRS + t;
        int sidx = ei[e];
        const ushort_t* xs = x + (size_t)sidx * (KK * CC);
        const ushort_t* xd = x + (size_t)n * (KK * CC);
        float acc = 0.0f;
        for (int c = 0; c < CC; c++) acc += (us2f(xs[c]) - us2f(xd[c])) * wsh[c];
        fs[t] = acc;
    }
    __syncthreads();
    if (t < 3) {
        float acc = 0.0f;
        #pragma unroll
        for (int j = 0; j < NBRS; j++) acc += fs[j] * dirn[(size_t)(n * NBRS + j) * 3 + t];
        out[n * 3 + t] = acc;
    }
}

extern "C" void kernel_launch(void* const* d_in, const int* in_sizes, int n_in,
                              void* d_out, int out_size, void* d_ws, size_t ws_size,
                              hipStream_t stream) {
    (void)in_sizes; (void)n_in; (void)out_size; (void)ws_size;
    const float* z       = (const float*)d_in[0];
    const float* frac    = (const float*)d_in[1];
    const int*   atype   = (const int*)d_in[2];
    const float* lengths = (const float*)d_in[4];
    const float* angles  = (const float*)d_in[5];
    const int*   batch   = (const int*)d_in[6];
    const int*   ei      = (const int*)d_in[7];
    const float* emb     = (const float*)d_in[8];
    const float* zproj   = (const float*)d_in[9];
    const float* Wd      = (const float*)d_in[10];
    const float* W1      = (const float*)d_in[11];
    const float* W2      = (const float*)d_in[12];
    const float* Wa      = (const float*)d_in[13];
    const float* ba      = (const float*)d_in[14];
    const float* wf      = (const float*)d_in[15];
    float* out = (float*)d_out;

    float* ws = (float*)d_ws;
    float* pos  = ws; ws += NN * 3 + 4;
    float* dist = ws; ws += EE;
    float* dirn = ws; ws += EE * 3;
    float* Ypad = ws; ws += (size_t)EE * 20;
    float* zc   = ws; ws += N_CRYST * CC;
    int*   bptr = (int*)ws; ws += 256 * 33 + 4;           // 8448 ints (+pad, 16B mult)
    unsigned char* bedge = (unsigned char*)ws; ws += (256 * 160) / 4;  // 40960 B
    ushort_t* xbf  = (ushort_t*)ws;                        // [NN][19][128] bf16
    ushort_t* Abf2 = xbf + (size_t)NN * KK * CC;           // [E][128] rbf bf16
    ushort_t* WT1  = Abf2 + (size_t)EE * 128;              // [8][256][256]
    ushort_t* WT2  = WT1 + (size_t)NLAYERS * 256 * 256;    // [8][128][256]

    k_pos<<<NN / 256, 256, 0, stream>>>(frac, lengths, angles, batch, pos);
    k_edge<<<EE / 256, 256, 0, stream>>>(ei, pos, dist, dirn, Ypad);
    k_bcsr<<<256, 64, 0, stream>>>(ei, bptr, bedge);
    k_rbfA<<<(EE * NBASIS) / 256, 256, 0, stream>>>(dist, Abf2);
    k_wt<<<(NLAYERS * (HIDDIM * 256 + CC * HIDDIM)) / 256, 256, 0, stream>>>(W1, Wd, W2, WT1, WT2);
    k_zc<<<(N_CRYST * CC) / 256, 256, 0, stream>>>(z, zproj, zc);
    k_xinit<<<(NN * KK * CC) / 256, 256, 0, stream>>>(atype, batch, emb, zc, xbf);

    {
        void* kargs[] = {(void*)&Abf2, (void*)&WT1, (void*)&WT2, (void*)&Ypad,
                         (void*)&xbf, (void*)&bptr, (void*)&bedge};
        hipLaunchCooperativeKernel((const void*)k_layers, dim3(256), dim3(512),
                                   kargs, 0, stream);
    }

    k_coord<<<NN, 64, 0, stream>>>(ei, xbf, wf, dirn, out);
    k_logits<<<(NN * MAXZV) / 256, 256, 0, stream>>>(xbf, Wa, ba, out + NN * 3);
}